// Round 27
// baseline (402.451 us; speedup 1.0000x reference)
//
#include <hip/hip_runtime.h>

// SinkhornAttention on MI355X — r26 + (1) gumbel fused into sinkvt (block b
// computes its own E_b; per-batch locality), (2) attn GEMM ported to the
// r24-verified 256^2 counted-vmcnt + T2-swizzle template (gemm256_att).
// cb_k accepted at ~91us (6 variants plateau — pattern-limited).
// T=S=4096, B=8, E=1024, BUCKET=16 -> nb=nkb=256. TAU=0.75, ITERS=8, SCALE=1/32.
// d_out = [ out | attn_weights | log_alpha ] f32.
// Noise (verified r7): threefry2x32 partitionable, counts (0,i), draw = o0 ^ o1.

typedef float    f32x4 __attribute__((ext_vector_type(4)));
typedef _Float16 h4    __attribute__((ext_vector_type(4)));
typedef _Float16 h8    __attribute__((ext_vector_type(8)));

#define OUT_ELEMS 33554432
#define AW_ELEMS  524288

__device__ __forceinline__ void gload16(const void* g, void* l) {
  __builtin_amdgcn_global_load_lds((__attribute__((address_space(1))) void*)g,
                                   (__attribute__((address_space(3))) void*)l,
                                   16, 0, 0);
}

__device__ __forceinline__ unsigned rotl32(unsigned x, int r) {
  return (x << r) | (x >> (32 - r));
}
// JAX threefry2x32 partitionable gumbel draw for element index i (verified r7).
__device__ __forceinline__ float gumbel_of(unsigned i) {
  const unsigned k0 = 0u, k1 = 42u, k2 = 0u ^ 42u ^ 0x1BD11BDAu;
  unsigned x0 = 0u + k0, x1 = i + k1;
#define R4(a,b,c,d) \
  x0 += x1; x1 = rotl32(x1, a); x1 ^= x0; \
  x0 += x1; x1 = rotl32(x1, b); x1 ^= x0; \
  x0 += x1; x1 = rotl32(x1, c); x1 ^= x0; \
  x0 += x1; x1 = rotl32(x1, d); x1 ^= x0;
  R4(13,15,26,6)  x0 += k1; x1 += k2 + 1u;
  R4(17,29,16,24) x0 += k2; x1 += k0 + 2u;
  R4(13,15,26,6)  x0 += k0; x1 += k1 + 3u;
  R4(17,29,16,24) x0 += k1; x1 += k2 + 4u;
  R4(13,15,26,6)  x0 += k2; x1 += k0 + 5u;
#undef R4
  unsigned bits = x0 ^ x1;
  float u = __builtin_bit_cast(float, (bits >> 9) | 0x3f800000u) - 1.0f;
  return -logf(-logf(u + 1e-6f) + 1e-6f);
}

// ---------------- fused: weight f32->f16 (blocks 0-3071) ∥ bucket mean -------
__global__ __launch_bounds__(256) void cb_k(const float* __restrict__ wq,
                                            const float* __restrict__ wk,
                                            const float* __restrict__ wo,
                                            _Float16* __restrict__ wdst,
                                            const float* __restrict__ q,
                                            const float* __restrict__ k,
                                            _Float16* __restrict__ qbar,
                                            _Float16* __restrict__ kbar) {
  __shared__ __attribute__((aligned(16))) float ldsbuf[8192];     // 32 KB
  int bid = blockIdx.x;
  int tid = threadIdx.x;
  if (bid < 3072) {
    int which = bid >> 10;
    const float* src = which == 0 ? wq : (which == 1 ? wk : wo);
    size_t idx = (size_t)(bid & 1023) * 256 + tid;
    f32x4 v = ((const f32x4*)src)[idx];
    ((h4*)(wdst + (size_t)which * 1048576))[idx] = __builtin_convertvector(v, h4);
  } else {
    int g = bid - 3072;                                           // 0..8191
    int srcid = g >> 12, ii = (g >> 4) & 255, bb = (g >> 1) & 7, eh = g & 1;
    const float* s2 = srcid ? k : q;
    _Float16* d2 = srcid ? kbar : qbar;
    const int grp = tid >> 7;
    const int wh  = (tid >> 6) & 1;
    const int col = tid & 127;
    #pragma unroll
    for (int jj = 0; jj < 8; ++jj) {
      int j = jj * 2 + grp;
      gload16(s2 + (size_t)((ii * 16 + j) * 8 + bb) * 1024 + eh * 512 + col * 4,
              &ldsbuf[j * 512 + wh * 256]);
    }
    __syncthreads();
    if (tid < 128) {
      f32x4 a = {0.f, 0.f, 0.f, 0.f};
      #pragma unroll
      for (int j = 0; j < 16; ++j)
        a += *(const f32x4*)&ldsbuf[j * 512 + tid * 4];
      a *= 0.0625f;
      ((h4*)(d2 + (size_t)(bb * 256 + ii) * 1024 + eh * 512))[tid] =
          __builtin_convertvector(a, h4);
    }
  }
}

// ---------------- fused: gumbel+sinkhorn (blocks 0-7) ∥ vtrans (blocks 8+) ---
// Sink block b first computes its own E_b = exp((logalpha+g)/tau) (64/thread,
// coalesced) into ebuf, syncs, then runs the verified scaling-vector loop.
__global__ __launch_bounds__(1024) void sinkvt_k(const float* __restrict__ logalpha,
                                                 float* __restrict__ ebuf,
                                                 float* __restrict__ attnw,
                                                 _Float16* __restrict__ wsh,
                                                 const float* __restrict__ v,
                                                 _Float16* __restrict__ vt) {
  __shared__ __attribute__((aligned(16))) char smem[36864];
  const int t = threadIdx.x;
  if (blockIdx.x < 8) {
    const int b = blockIdx.x;
    // ---- in-block gumbel: E_b (65536 elems, 64/thread) ----
    for (int u = 0; u < 64; ++u) {
      unsigned ig = (unsigned)b * 65536 + (unsigned)u * 1024 + t;
      ebuf[ig] = __expf((logalpha[ig] + gumbel_of(ig)) / 0.75f);
    }
    __syncthreads();

    const int r = t >> 2, p = t & 3;       // row-sweep role
    const int k = t & 255, g = t >> 8;     // col-sweep role
    const float* Eb = ebuf + (size_t)b * 65536;
    const f32x4* Eb4 = (const f32x4*)Eb;
    float* ra = (float*)smem;                       // 256
    float* cb = ra + 256;                           // 256
    float (*part)[256] = (float (*)[256])(cb + 256);// 4x256
    if (t < 256) cb[t] = 1.0f;
    __syncthreads();
    const f32x4* cb4 = (const f32x4*)cb;

    for (int it = 0; it < 8; ++it) {
      float s = 0.f;
      #pragma unroll
      for (int i = 0; i < 16; ++i) {
        f32x4 e = Eb4[r * 64 + p * 16 + i];
        f32x4 c = cb4[p * 16 + i];
        f32x4 m = e * c;
        s += (m[0] + m[1]) + (m[2] + m[3]);
      }
      s += __shfl_xor(s, 1, 64);
      s += __shfl_xor(s, 2, 64);
      if (p == 0) ra[r] = 1.0f / s;
      __syncthreads();
      float s2 = 0.f;
      #pragma unroll 8
      for (int q2 = 0; q2 < 64; ++q2) {
        int row = g * 64 + q2;
        s2 += Eb[row * 256 + k] * ra[row];
      }
      part[g][k] = s2;
      __syncthreads();
      if (t < 256) {
        cb[t] = 1.0f / (part[0][t] + part[1][t] + part[2][t] + part[3][t]);
      }
      __syncthreads();
    }

    const float arow = ra[r];
    f32x4* aw = (f32x4*)(attnw + (size_t)b * 65536 + r * 256 + p * 64);
    h4* wh = (h4*)(wsh + (size_t)b * 65536 + r * 256 + p * 64);
    #pragma unroll
    for (int i = 0; i < 16; ++i) {
      f32x4 e = Eb4[r * 64 + p * 16 + i];
      f32x4 c = cb4[p * 16 + i];
      f32x4 w = e * c * arow;
      aw[i] = w;
      h4 hv;
      hv[0] = (_Float16)w[0]; hv[1] = (_Float16)w[1];
      hv[2] = (_Float16)w[2]; hv[3] = (_Float16)w[3];
      wh[i] = hv;
    }
  } else {
    const int s = t >> 8, t2 = t & 255;
    int bid = (blockIdx.x - 8) * 4 + s;              // 0..8191
    _Float16 (*tile)[72] = (_Float16 (*)[72])(smem + s * 9216);
    int kb = bid & 3, eb = (bid >> 2) & 15, j = (bid >> 6) & 15;
    int b = ((bid >> 10) + (bid & 7)) & 7;  // diagonal decode (r22)
    int k0 = kb * 64, e0 = eb * 64;
    int r = t2 >> 2, qq = t2 & 3;
    const float* src = v + ((size_t)((k0 + r) * 16 + j) * 8 + b) * 1024 + e0;
    #pragma unroll
    for (int ii = 0; ii < 4; ++ii) {
      f32x4 x = ((const f32x4*)src)[qq + ii * 4];
      *(h4*)&tile[r][(qq + ii * 4) * 4] = __builtin_convertvector(x, h4);
    }
    __syncthreads();
    _Float16* dstp = vt + (((size_t)(b * 16 + j) * 1024 + e0 + r) * 256 + k0 + qq * 16);
    h8 o0, o1;
    #pragma unroll
    for (int kk = 0; kk < 8; ++kk) o0[kk] = tile[qq * 16 + kk][r];
    #pragma unroll
    for (int kk = 0; kk < 8; ++kk) o1[kk] = tile[qq * 16 + 8 + kk][r];
    *(h8*)dstp = o0;
    *(h8*)(dstp + 8) = o1;
  }
}

// ---------------- generic 128x128 NT MFMA GEMM (m97 structure) ---------------
// MODE 0: proj (grid 128 x 1 x 2, z = q/k) -> f16 out + bias (z-strided slabs)
// MODE 1: logits  (3-D grid)               -> f32 /32 to log_alpha
template <int MODE>
__global__ __launch_bounds__(256) void gemm128(const _Float16* __restrict__ A,
                                               const _Float16* __restrict__ B,
                                               const float* __restrict__ bias,
                                               const float* __restrict__ bias2,
                                               void* __restrict__ out0,
                                               int K, int lda, int ldb) {
  const int tid = threadIdx.x, lane = tid & 63, w = tid >> 6;
  int bx = blockIdx.x, by = blockIdx.y, bz = blockIdx.z;
  if constexpr (MODE == 0) {
    int wid = ((bx & 7) << 4) + (bx >> 3);
    by = wid & 7; bx = wid >> 3;
  }
  const int m0 = bx * 128, n0 = by * 128;
  const _Float16* Ab = A;
  const _Float16* Bb = B;
  const float* bs = bias;
  if constexpr (MODE == 0) {
    Ab += (size_t)bz * 2097152;        // qbar -> kbar
    Bb += (size_t)bz * 1048576;        // wqh  -> wkh
    if (bz) bs = bias2;                // bq   -> bk
  }
  if constexpr (MODE == 1) { Ab += (size_t)bz * 262144; Bb += (size_t)bz * 262144; }
  __shared__ _Float16 lA[128 * 32];
  __shared__ _Float16 lB[128 * 32];
  f32x4 acc[4][4] = {};
  const int wm = (w >> 1) * 64, wn = (w & 1) * 64;
  const int fr = lane & 15, fk = (lane >> 4) * 8;
  const int q0 = tid, q1 = tid + 256;

  for (int kt = 0; kt < K; kt += 32) {
    __syncthreads();
    gload16(Ab + (size_t)(m0 + (q0 >> 2)) * lda + kt + (q0 & 3) * 8, &lA[(w * 64) * 8]);
    gload16(Ab + (size_t)(m0 + (q1 >> 2)) * lda + kt + (q1 & 3) * 8, &lA[(256 + w * 64) * 8]);
    gload16(Bb + (size_t)(n0 + (q0 >> 2)) * ldb + kt + (q0 & 3) * 8, &lB[(w * 64) * 8]);
    gload16(Bb + (size_t)(n0 + (q1 >> 2)) * ldb + kt + (q1 & 3) * 8, &lB[(256 + w * 64) * 8]);
    __syncthreads();
    h8 af[4], bf[4];
    #pragma unroll
    for (int i = 0; i < 4; ++i) {
      af[i] = *(const h8*)&lA[(wm + i * 16 + fr) * 32 + fk];
      bf[i] = *(const h8*)&lB[(wn + i * 16 + fr) * 32 + fk];
    }
    #pragma unroll
    for (int mi = 0; mi < 4; ++mi)
      #pragma unroll
      for (int ni = 0; ni < 4; ++ni)
        acc[mi][ni] = __builtin_amdgcn_mfma_f32_16x16x32_f16(af[mi], bf[ni], acc[mi][ni], 0, 0, 0);
  }

  const int er = (lane >> 4) * 4;
  #pragma unroll
  for (int mi = 0; mi < 4; ++mi) {
    #pragma unroll
    for (int ni = 0; ni < 4; ++ni) {
      #pragma unroll
      for (int r = 0; r < 4; ++r) {
        int row = m0 + wm + mi * 16 + er + r;
        int col = n0 + wn + ni * 16 + fr;
        float val = acc[mi][ni][r];
        if constexpr (MODE == 0) {
          ((_Float16*)out0)[(size_t)bz * 2097152 + (size_t)row * 1024 + col] =
              (_Float16)(val + bs[col]);
        } else {
          ((float*)out0)[(size_t)bz * 65536 + row * 256 + col] = val * 0.03125f;
        }
      }
    }
  }
}

// ---------------- attn: 256-row tile, BK=64, counted-vmcnt + T2 swizzle ------
// Per (b,j): attnh[(b*4096+row*16+j)*1024+col] = wsh_b[row][:].vt_bj[col][:]
// Grid 512 = 128 bj x 4 n-tiles. M=256 (1 tile), K=256 (4 tiles).
__global__ __launch_bounds__(512, 1) void gemm256_att(const _Float16* __restrict__ W,
                                                      const _Float16* __restrict__ V,
                                                      _Float16* __restrict__ attnh) {
  extern __shared__ __align__(16) _Float16 dsm[];
  _Float16 (*lA)[16384] = (_Float16 (*)[16384])dsm;             // [2][256*64]
  _Float16 (*lB)[16384] = (_Float16 (*)[16384])(dsm + 32768);
  const int tid = threadIdx.x, lane = tid & 63, w = tid >> 6;
  const int wr = w >> 2, wc = w & 3;
  int bx = blockIdx.x;
  int wid = ((bx & 7) << 6) + (bx >> 3);                        // XCD chunk of 64
  const int bj = wid >> 2, nt = wid & 3;
  const int b = bj >> 4, j = bj & 15;
  const int n0 = nt * 256;
  const _Float16* A = W + (size_t)b * 65536;                    // [256][256]
  const _Float16* B = V + (size_t)bj * 262144;                  // [1024][256]
  const int fr = lane & 15, fk = (lane >> 4) * 8;
  const int sx = (lane & 7) << 3;
  const int c0 = fk ^ sx, c1 = (fk + 32) ^ sx;
  f32x4 acc[8][4] = {};

#define STAGE(t, buf) { \
    const int cs = ((tid & 7) ^ ((tid >> 3) & 7)) * 8; \
    const _Float16* Ag = A + (size_t)(tid >> 3) * 256 + (t) * 64 + cs; \
    const _Float16* Bg = B + (size_t)(n0 + (tid >> 3)) * 256 + (t) * 64 + cs; \
    _Float16* la0 = &lA[buf][w * 512]; \
    _Float16* lb0 = &lB[buf][w * 512]; \
    gload16(Ag,              la0); \
    gload16(Ag +  64 * 256,  la0 + 4096); \
    gload16(Ag + 128 * 256,  la0 + 8192); \
    gload16(Ag + 192 * 256,  la0 + 12288); \
    gload16(Bg,              lb0); \
    gload16(Bg +  64 * 256,  lb0 + 4096); \
    gload16(Bg + 128 * 256,  lb0 + 8192); \
    gload16(Bg + 192 * 256,  lb0 + 12288); \
  }

  STAGE(0, 0)
  STAGE(1, 1)

  for (int t = 0; t < 4; ++t) {
    const int bt = t & 1;
    if (t < 3) { asm volatile("s_waitcnt vmcnt(8)" ::: "memory"); }
    else       { asm volatile("s_waitcnt vmcnt(0)" ::: "memory"); }
    __builtin_amdgcn_s_barrier();
    h8 a0[8], b0[4];
    #pragma unroll
    for (int mi = 0; mi < 8; ++mi)
      a0[mi] = *(const h8*)&lA[bt][(wr * 128 + mi * 16 + fr) * 64 + c0];
    #pragma unroll
    for (int ni = 0; ni < 4; ++ni)
      b0[ni] = *(const h8*)&lB[bt][(wc * 64 + ni * 16 + fr) * 64 + c0];
    #pragma unroll
    for (int mi = 0; mi < 8; ++mi)
      #pragma unroll
      for (int ni = 0; ni < 4; ++ni)
        acc[mi][ni] = __builtin_amdgcn_mfma_f32_16x16x32_f16(a0[mi], b0[ni], acc[mi][ni], 0, 0, 0);
    h8 a1[8], b1[4];
    #pragma unroll
    for (int mi = 0; mi < 8; ++mi)
      a1[mi] = *(const h8*)&lA[bt][(wr * 128 + mi * 16 + fr) * 64 + c1];
    #pragma unroll
    for (int ni = 0; ni < 4; ++ni)
      b1[ni] = *(const h8*)&lB[bt][(wc * 64 + ni * 16 + fr) * 64 + c1];
    asm volatile("s_waitcnt lgkmcnt(0)" ::: "memory");
    __builtin_amdgcn_sched_barrier(0);
    __builtin_amdgcn_s_barrier();
    if (t + 2 < 4) STAGE(t + 2, bt)
    __builtin_amdgcn_sched_barrier(0);
    __builtin_amdgcn_s_setprio(1);
    #pragma unroll
    for (int mi = 0; mi < 8; ++mi)
      #pragma unroll
      for (int ni = 0; ni < 4; ++ni)
        acc[mi][ni] = __builtin_amdgcn_mfma_f32_16x16x32_f16(a1[mi], b1[ni], acc[mi][ni], 0, 0, 0);
    __builtin_amdgcn_s_setprio(0);
  }
#undef STAGE

  const int er = (lane >> 4) * 4;
  #pragma unroll
  for (int mi = 0; mi < 8; ++mi) {
    #pragma unroll
    for (int ni = 0; ni < 4; ++ni) {
      #pragma unroll
      for (int r = 0; r < 4; ++r) {
        int row = wr * 128 + mi * 16 + er + r;        // q-bucket 0..255
        int col = n0 + wc * 64 + ni * 16 + fr;        // e 0..1023
        attnh[((size_t)(b * 4096 + row * 16 + j)) * 1024 + col] =
            (_Float16)acc[mi][ni][r];
      }
    }
  }
}

// ---------------- outproj: 256x256 tile, BK=64, counted-vmcnt + T2 swizzle ---
__global__ __launch_bounds__(512, 1) void gemm256_out(const _Float16* __restrict__ A,
                                                      const _Float16* __restrict__ B,
                                                      const float* __restrict__ bias,
                                                      float* __restrict__ out) {
  extern __shared__ __align__(16) _Float16 dsm[];
  _Float16 (*lA)[16384] = (_Float16 (*)[16384])dsm;             // [2][256*64]
  _Float16 (*lB)[16384] = (_Float16 (*)[16384])(dsm + 32768);
  const int tid = threadIdx.x, lane = tid & 63, w = tid >> 6;
  const int wr = w >> 2, wc = w & 3;
  int bx = blockIdx.x;
  int wid = ((bx & 7) << 6) + (bx >> 3);                        // XCD chunk of 64
  const int m0 = (wid >> 2) * 256, n0 = (wid & 3) * 256;
  const int fr = lane & 15, fk = (lane >> 4) * 8;
  const int sx = (lane & 7) << 3;
  const int c0 = fk ^ sx, c1 = (fk + 32) ^ sx;
  f32x4 acc[8][4] = {};

#define STAGE(t, buf) { \
    const int cs = ((tid & 7) ^ ((tid >> 3) & 7)) * 8; \
    const _Float16* Ag = A + (size_t)(m0 + (tid >> 3)) * 1024 + (t) * 64 + cs; \
    const _Float16* Bg = B + (size_t)(n0 + (tid >> 3)) * 1024 + (t) * 64 + cs; \
    _Float16* la0 = &lA[buf][w * 512]; \
    _Float16* lb0 = &lB[buf][w * 512]; \
    gload16(Ag,               la0); \
    gload16(Ag +  64 * 1024,  la0 + 4096); \
    gload16(Ag + 128 * 1024,  la0 + 8192); \
    gload16(Ag + 192 * 1024,  la0 + 12288); \
    gload16(Bg,               lb0); \
    gload16(Bg +  64 * 1024,  lb0 + 4096); \
    gload16(Bg + 128 * 1024,  lb0 + 8192); \
    gload16(Bg + 192 * 1024,  lb0 + 12288); \
  }

  STAGE(0, 0)
  STAGE(1, 1)

  for (int t = 0; t < 16; ++t) {
    const int bt = t & 1;
    if (t < 15) { asm volatile("s_waitcnt vmcnt(8)" ::: "memory"); }
    else        { asm volatile("s_waitcnt vmcnt(0)" ::: "memory"); }
    __builtin_amdgcn_s_barrier();
    h8 a0[8], b0[4];
    #pragma unroll
    for (int mi = 0; mi < 8; ++mi)
      a0[mi] = *(const h8*)&lA[bt][(wr * 128 + mi * 16 + fr) * 64 + c0];
    #pragma unroll
    for (int ni = 0; ni < 4; ++ni)
      b0[ni] = *(const h8*)&lB[bt][(wc * 64 + ni * 16 + fr) * 64 + c0];
    #pragma unroll
    for (int mi = 0; mi < 8; ++mi)
      #pragma unroll
      for (int ni = 0; ni < 4; ++ni)
        acc[mi][ni] = __builtin_amdgcn_mfma_f32_16x16x32_f16(a0[mi], b0[ni], acc[mi][ni], 0, 0, 0);
    h8 a1[8], b1[4];
    #pragma unroll
    for (int mi = 0; mi < 8; ++mi)
      a1[mi] = *(const h8*)&lA[bt][(wr * 128 + mi * 16 + fr) * 64 + c1];
    #pragma unroll
    for (int ni = 0; ni < 4; ++ni)
      b1[ni] = *(const h8*)&lB[bt][(wc * 64 + ni * 16 + fr) * 64 + c1];
    asm volatile("s_waitcnt lgkmcnt(0)" ::: "memory");
    __builtin_amdgcn_sched_barrier(0);
    __builtin_amdgcn_s_barrier();
    if (t + 2 < 16) STAGE(t + 2, bt)
    __builtin_amdgcn_sched_barrier(0);
    __builtin_amdgcn_s_setprio(1);
    #pragma unroll
    for (int mi = 0; mi < 8; ++mi)
      #pragma unroll
      for (int ni = 0; ni < 4; ++ni)
        acc[mi][ni] = __builtin_amdgcn_mfma_f32_16x16x32_f16(a1[mi], b1[ni], acc[mi][ni], 0, 0, 0);
    __builtin_amdgcn_s_setprio(0);
  }
#undef STAGE

  const int er = (lane >> 4) * 4;
  #pragma unroll
  for (int mi = 0; mi < 8; ++mi) {
    #pragma unroll
    for (int ni = 0; ni < 4; ++ni) {
      #pragma unroll
      for (int r = 0; r < 4; ++r) {
        int row = m0 + wr * 128 + mi * 16 + er + r;   // = b*4096 + t
        int col = n0 + wc * 64 + ni * 16 + fr;
        int bb = row >> 12, tt = row & 4095;
        out[((size_t)tt * 8 + bb) * 1024 + col] = acc[mi][ni][r] + bias[col];
      }
    }
  }
}

// -----------------------------------------------------------------------------
extern "C" void kernel_launch(void* const* d_in, const int* in_sizes, int n_in,
                              void* d_out, int out_size, void* d_ws, size_t ws_size,
                              hipStream_t stream) {
  const float* query = (const float*)d_in[0];
  const float* key   = (const float*)d_in[1];
  const float* value = (const float*)d_in[2];
  const float* wq    = (const float*)d_in[3];
  const float* bq    = (const float*)d_in[4];
  const float* wk    = (const float*)d_in[5];
  const float* bk    = (const float*)d_in[6];
  const float* wo    = (const float*)d_in[7];
  const float* bo    = (const float*)d_in[8];

  float* out      = (float*)d_out;
  float* attnw    = out + OUT_ELEMS;            // 8*256*256
  float* logalpha = out + OUT_ELEMS + AW_ELEMS; // logits (pre-noise)

  char* ws = (char*)d_ws;
  const size_t MB = 1024 * 1024;
  _Float16* wqh   = (_Float16*)(ws + 0 * MB);   // 2 MB  (wkh at +2MB, woh at +4MB)
  _Float16* woh   = (_Float16*)(ws + 4 * MB);   // 2 MB
  _Float16* qbar  = (_Float16*)(ws + 6 * MB);   // 4 MB  (2048x1024; kbar at +4MB)
  _Float16* kbar  = (_Float16*)(ws + 10 * MB);  // 4 MB
  _Float16* qbh   = (_Float16*)(ws + 14 * MB);  // 4 MB  (kbh at +4MB)
  _Float16* kbh   = (_Float16*)(ws + 18 * MB);  // 4 MB
  float*    ebuf  = (float*)(ws + 22 * MB);     // 2 MB  exp-domain entries
  _Float16* wsh   = (_Float16*)(ws + 25 * MB);  // 1 MB  attn weights f16
  _Float16* vt    = (_Float16*)(ws + 26 * MB);  // 64 MB vt[b][j][e][k]
  _Float16* attnh = (_Float16*)(ws + 90 * MB);  // 64 MB attn (B,T,E) f16
  (void)in_sizes; (void)n_in; (void)out_size; (void)ws_size;

  cb_k<<<dim3(11264), 256, 0, stream>>>(wq, wk, wo, wqh, query, key, qbar, kbar);

  gemm128<0><<<dim3(128, 1, 2), 256, 0, stream>>>(qbar, wqh, bq, bk, qbh, 1024, 1024, 1024);
  gemm128<1><<<dim3(2, 2, 8), 256, 0, stream>>>(qbh, kbh, nullptr, nullptr, logalpha, 1024, 1024, 1024);

  sinkvt_k<<<dim3(2056), 1024, 0, stream>>>(logalpha, ebuf, attnw, wsh, value, vt);

  gemm256_att<<<dim3(512), 512, 131072, stream>>>(wsh, vt, attnh);
  gemm256_out<<<dim3(512), 512, 131072, stream>>>(attnh, woh, bo, out);
}

// Round 28
// 322.588 us; speedup vs baseline: 1.2476x; 1.2476x over previous
//
#include <hip/hip_runtime.h>

// SinkhornAttention on MI355X — r26 base + gemm256_att (the working half of
// r27). r27 lesson: fusing gumbel into the 8-block sink branch concentrated
// 524K transcendental evals on 8 CUs (163us!) — reverted to standalone
// gumbel_k on 2048 blocks.
// T=S=4096, B=8, E=1024, BUCKET=16 -> nb=nkb=256. TAU=0.75, ITERS=8, SCALE=1/32.
// d_out = [ out | attn_weights | log_alpha ] f32.
// Noise (verified r7): threefry2x32 partitionable, counts (0,i), draw = o0 ^ o1.

typedef float    f32x4 __attribute__((ext_vector_type(4)));
typedef _Float16 h4    __attribute__((ext_vector_type(4)));
typedef _Float16 h8    __attribute__((ext_vector_type(8)));

#define OUT_ELEMS 33554432
#define AW_ELEMS  524288

__device__ __forceinline__ void gload16(const void* g, void* l) {
  __builtin_amdgcn_global_load_lds((__attribute__((address_space(1))) void*)g,
                                   (__attribute__((address_space(3))) void*)l,
                                   16, 0, 0);
}

// ---------------- fused: weight f32->f16 (blocks 0-3071) ∥ bucket mean -------
__global__ __launch_bounds__(256) void cb_k(const float* __restrict__ wq,
                                            const float* __restrict__ wk,
                                            const float* __restrict__ wo,
                                            _Float16* __restrict__ wdst,
                                            const float* __restrict__ q,
                                            const float* __restrict__ k,
                                            _Float16* __restrict__ qbar,
                                            _Float16* __restrict__ kbar) {
  __shared__ __attribute__((aligned(16))) float ldsbuf[8192];     // 32 KB
  int bid = blockIdx.x;
  int tid = threadIdx.x;
  if (bid < 3072) {
    int which = bid >> 10;
    const float* src = which == 0 ? wq : (which == 1 ? wk : wo);
    size_t idx = (size_t)(bid & 1023) * 256 + tid;
    f32x4 v = ((const f32x4*)src)[idx];
    ((h4*)(wdst + (size_t)which * 1048576))[idx] = __builtin_convertvector(v, h4);
  } else {
    int g = bid - 3072;                                           // 0..8191
    int srcid = g >> 12, ii = (g >> 4) & 255, bb = (g >> 1) & 7, eh = g & 1;
    const float* s2 = srcid ? k : q;
    _Float16* d2 = srcid ? kbar : qbar;
    const int grp = tid >> 7;
    const int wh  = (tid >> 6) & 1;
    const int col = tid & 127;
    #pragma unroll
    for (int jj = 0; jj < 8; ++jj) {
      int j = jj * 2 + grp;
      gload16(s2 + (size_t)((ii * 16 + j) * 8 + bb) * 1024 + eh * 512 + col * 4,
              &ldsbuf[j * 512 + wh * 256]);
    }
    __syncthreads();
    if (tid < 128) {
      f32x4 a = {0.f, 0.f, 0.f, 0.f};
      #pragma unroll
      for (int j = 0; j < 16; ++j)
        a += *(const f32x4*)&ldsbuf[j * 512 + tid * 4];
      a *= 0.0625f;
      ((h4*)(d2 + (size_t)(bb * 256 + ii) * 1024 + eh * 512))[tid] =
          __builtin_convertvector(a, h4);
    }
  }
}

// ---------------- JAX threefry2x32 gumbel (verified r7) ----------------------
__device__ __forceinline__ unsigned rotl32(unsigned x, int r) {
  return (x << r) | (x >> (32 - r));
}
__global__ __launch_bounds__(256) void gumbel_k(const float* __restrict__ logits,
                                                float* __restrict__ ebuf) {
  unsigned i = blockIdx.x * 256 + threadIdx.x;                    // 0..524287
  const unsigned k0 = 0u, k1 = 42u, k2 = 0u ^ 42u ^ 0x1BD11BDAu;
  unsigned x0 = 0u + k0, x1 = i + k1;                             // counts (hi,lo)=(0,i)
#define R4(a,b,c,d) \
  x0 += x1; x1 = rotl32(x1, a); x1 ^= x0; \
  x0 += x1; x1 = rotl32(x1, b); x1 ^= x0; \
  x0 += x1; x1 = rotl32(x1, c); x1 ^= x0; \
  x0 += x1; x1 = rotl32(x1, d); x1 ^= x0;
  R4(13,15,26,6)  x0 += k1; x1 += k2 + 1u;
  R4(17,29,16,24) x0 += k2; x1 += k0 + 2u;
  R4(13,15,26,6)  x0 += k0; x1 += k1 + 3u;
  R4(17,29,16,24) x0 += k1; x1 += k2 + 4u;
  R4(13,15,26,6)  x0 += k2; x1 += k0 + 5u;
#undef R4
  unsigned bits = x0 ^ x1;
  float u = __builtin_bit_cast(float, (bits >> 9) | 0x3f800000u) - 1.0f;
  float g = -logf(-logf(u + 1e-6f) + 1e-6f);
  ebuf[i] = __expf((logits[i] + g) / 0.75f);
}

// ---------------- fused: sinkhorn (blocks 0-7) ∥ V-transpose (blocks 8+) -----
__global__ __launch_bounds__(1024) void sinkvt_k(const float* __restrict__ ein,
                                                 float* __restrict__ attnw,
                                                 _Float16* __restrict__ wsh,
                                                 const float* __restrict__ v,
                                                 _Float16* __restrict__ vt) {
  __shared__ __attribute__((aligned(16))) char smem[36864];
  const int t = threadIdx.x;
  if (blockIdx.x < 8) {
    const int b = blockIdx.x;
    const int r = t >> 2, p = t & 3;       // row-sweep role
    const int k = t & 255, g = t >> 8;     // col-sweep role
    const float* Eb = ein + (size_t)b * 65536;
    const f32x4* Eb4 = (const f32x4*)Eb;
    float* ra = (float*)smem;                       // 256
    float* cb = ra + 256;                           // 256
    float (*part)[256] = (float (*)[256])(cb + 256);// 4x256
    if (t < 256) cb[t] = 1.0f;
    __syncthreads();
    const f32x4* cb4 = (const f32x4*)cb;

    for (int it = 0; it < 8; ++it) {
      float s = 0.f;
      #pragma unroll
      for (int i = 0; i < 16; ++i) {
        f32x4 e = Eb4[r * 64 + p * 16 + i];
        f32x4 c = cb4[p * 16 + i];
        f32x4 m = e * c;
        s += (m[0] + m[1]) + (m[2] + m[3]);
      }
      s += __shfl_xor(s, 1, 64);
      s += __shfl_xor(s, 2, 64);
      if (p == 0) ra[r] = 1.0f / s;
      __syncthreads();
      float s2 = 0.f;
      #pragma unroll 8
      for (int q2 = 0; q2 < 64; ++q2) {
        int row = g * 64 + q2;
        s2 += Eb[row * 256 + k] * ra[row];
      }
      part[g][k] = s2;
      __syncthreads();
      if (t < 256) {
        cb[t] = 1.0f / (part[0][t] + part[1][t] + part[2][t] + part[3][t]);
      }
      __syncthreads();
    }

    const float arow = ra[r];
    f32x4* aw = (f32x4*)(attnw + (size_t)b * 65536 + r * 256 + p * 64);
    h4* wh = (h4*)(wsh + (size_t)b * 65536 + r * 256 + p * 64);
    #pragma unroll
    for (int i = 0; i < 16; ++i) {
      f32x4 e = Eb4[r * 64 + p * 16 + i];
      f32x4 c = cb4[p * 16 + i];
      f32x4 w = e * c * arow;
      aw[i] = w;
      h4 hv;
      hv[0] = (_Float16)w[0]; hv[1] = (_Float16)w[1];
      hv[2] = (_Float16)w[2]; hv[3] = (_Float16)w[3];
      wh[i] = hv;
    }
  } else {
    const int s = t >> 8, t2 = t & 255;
    int bid = (blockIdx.x - 8) * 4 + s;              // 0..8191
    _Float16 (*tile)[72] = (_Float16 (*)[72])(smem + s * 9216);
    int kb = bid & 3, eb = (bid >> 2) & 15, j = (bid >> 6) & 15;
    int b = ((bid >> 10) + (bid & 7)) & 7;  // diagonal decode (r22)
    int k0 = kb * 64, e0 = eb * 64;
    int r = t2 >> 2, qq = t2 & 3;
    const float* src = v + ((size_t)((k0 + r) * 16 + j) * 8 + b) * 1024 + e0;
    #pragma unroll
    for (int ii = 0; ii < 4; ++ii) {
      f32x4 x = ((const f32x4*)src)[qq + ii * 4];
      *(h4*)&tile[r][(qq + ii * 4) * 4] = __builtin_convertvector(x, h4);
    }
    __syncthreads();
    _Float16* dstp = vt + (((size_t)(b * 16 + j) * 1024 + e0 + r) * 256 + k0 + qq * 16);
    h8 o0, o1;
    #pragma unroll
    for (int kk = 0; kk < 8; ++kk) o0[kk] = tile[qq * 16 + kk][r];
    #pragma unroll
    for (int kk = 0; kk < 8; ++kk) o1[kk] = tile[qq * 16 + 8 + kk][r];
    *(h8*)dstp = o0;
    *(h8*)(dstp + 8) = o1;
  }
}

// ---------------- generic 128x128 NT MFMA GEMM (m97 structure) ---------------
// MODE 0: proj (grid 128 x 1 x 2, z = q/k) -> f16 out + bias (z-strided slabs)
// MODE 1: logits  (3-D grid)               -> f32 /32 to log_alpha
template <int MODE>
__global__ __launch_bounds__(256) void gemm128(const _Float16* __restrict__ A,
                                               const _Float16* __restrict__ B,
                                               const float* __restrict__ bias,
                                               const float* __restrict__ bias2,
                                               void* __restrict__ out0,
                                               int K, int lda, int ldb) {
  const int tid = threadIdx.x, lane = tid & 63, w = tid >> 6;
  int bx = blockIdx.x, by = blockIdx.y, bz = blockIdx.z;
  if constexpr (MODE == 0) {
    int wid = ((bx & 7) << 4) + (bx >> 3);
    by = wid & 7; bx = wid >> 3;
  }
  const int m0 = bx * 128, n0 = by * 128;
  const _Float16* Ab = A;
  const _Float16* Bb = B;
  const float* bs = bias;
  if constexpr (MODE == 0) {
    Ab += (size_t)bz * 2097152;        // qbar -> kbar
    Bb += (size_t)bz * 1048576;        // wqh  -> wkh
    if (bz) bs = bias2;                // bq   -> bk
  }
  if constexpr (MODE == 1) { Ab += (size_t)bz * 262144; Bb += (size_t)bz * 262144; }
  __shared__ _Float16 lA[128 * 32];
  __shared__ _Float16 lB[128 * 32];
  f32x4 acc[4][4] = {};
  const int wm = (w >> 1) * 64, wn = (w & 1) * 64;
  const int fr = lane & 15, fk = (lane >> 4) * 8;
  const int q0 = tid, q1 = tid + 256;

  for (int kt = 0; kt < K; kt += 32) {
    __syncthreads();
    gload16(Ab + (size_t)(m0 + (q0 >> 2)) * lda + kt + (q0 & 3) * 8, &lA[(w * 64) * 8]);
    gload16(Ab + (size_t)(m0 + (q1 >> 2)) * lda + kt + (q1 & 3) * 8, &lA[(256 + w * 64) * 8]);
    gload16(Bb + (size_t)(n0 + (q0 >> 2)) * ldb + kt + (q0 & 3) * 8, &lB[(w * 64) * 8]);
    gload16(Bb + (size_t)(n0 + (q1 >> 2)) * ldb + kt + (q1 & 3) * 8, &lB[(256 + w * 64) * 8]);
    __syncthreads();
    h8 af[4], bf[4];
    #pragma unroll
    for (int i = 0; i < 4; ++i) {
      af[i] = *(const h8*)&lA[(wm + i * 16 + fr) * 32 + fk];
      bf[i] = *(const h8*)&lB[(wn + i * 16 + fr) * 32 + fk];
    }
    #pragma unroll
    for (int mi = 0; mi < 4; ++mi)
      #pragma unroll
      for (int ni = 0; ni < 4; ++ni)
        acc[mi][ni] = __builtin_amdgcn_mfma_f32_16x16x32_f16(af[mi], bf[ni], acc[mi][ni], 0, 0, 0);
  }

  const int er = (lane >> 4) * 4;
  #pragma unroll
  for (int mi = 0; mi < 4; ++mi) {
    #pragma unroll
    for (int ni = 0; ni < 4; ++ni) {
      #pragma unroll
      for (int r = 0; r < 4; ++r) {
        int row = m0 + wm + mi * 16 + er + r;
        int col = n0 + wn + ni * 16 + fr;
        float val = acc[mi][ni][r];
        if constexpr (MODE == 0) {
          ((_Float16*)out0)[(size_t)bz * 2097152 + (size_t)row * 1024 + col] =
              (_Float16)(val + bs[col]);
        } else {
          ((float*)out0)[(size_t)bz * 65536 + row * 256 + col] = val * 0.03125f;
        }
      }
    }
  }
}

// ---------------- attn: 256-row tile, BK=64, counted-vmcnt + T2 swizzle ------
// Per (b,j): attnh[(b*4096+row*16+j)*1024+col] = wsh_b[row][:].vt_bj[col][:]
// Grid 512 = 128 bj x 4 n-tiles. M=256 (1 tile), K=256 (4 tiles).
__global__ __launch_bounds__(512, 1) void gemm256_att(const _Float16* __restrict__ W,
                                                      const _Float16* __restrict__ V,
                                                      _Float16* __restrict__ attnh) {
  extern __shared__ __align__(16) _Float16 dsm[];
  _Float16 (*lA)[16384] = (_Float16 (*)[16384])dsm;             // [2][256*64]
  _Float16 (*lB)[16384] = (_Float16 (*)[16384])(dsm + 32768);
  const int tid = threadIdx.x, lane = tid & 63, w = tid >> 6;
  const int wr = w >> 2, wc = w & 3;
  int bx = blockIdx.x;
  int wid = ((bx & 7) << 6) + (bx >> 3);                        // XCD chunk of 64
  const int bj = wid >> 2, nt = wid & 3;
  const int b = bj >> 4, j = bj & 15;
  const int n0 = nt * 256;
  const _Float16* A = W + (size_t)b * 65536;                    // [256][256]
  const _Float16* B = V + (size_t)bj * 262144;                  // [1024][256]
  const int fr = lane & 15, fk = (lane >> 4) * 8;
  const int sx = (lane & 7) << 3;
  const int c0 = fk ^ sx, c1 = (fk + 32) ^ sx;
  f32x4 acc[8][4] = {};

#define STAGE(t, buf) { \
    const int cs = ((tid & 7) ^ ((tid >> 3) & 7)) * 8; \
    const _Float16* Ag = A + (size_t)(tid >> 3) * 256 + (t) * 64 + cs; \
    const _Float16* Bg = B + (size_t)(n0 + (tid >> 3)) * 256 + (t) * 64 + cs; \
    _Float16* la0 = &lA[buf][w * 512]; \
    _Float16* lb0 = &lB[buf][w * 512]; \
    gload16(Ag,              la0); \
    gload16(Ag +  64 * 256,  la0 + 4096); \
    gload16(Ag + 128 * 256,  la0 + 8192); \
    gload16(Ag + 192 * 256,  la0 + 12288); \
    gload16(Bg,              lb0); \
    gload16(Bg +  64 * 256,  lb0 + 4096); \
    gload16(Bg + 128 * 256,  lb0 + 8192); \
    gload16(Bg + 192 * 256,  lb0 + 12288); \
  }

  STAGE(0, 0)
  STAGE(1, 1)

  for (int t = 0; t < 4; ++t) {
    const int bt = t & 1;
    if (t < 3) { asm volatile("s_waitcnt vmcnt(8)" ::: "memory"); }
    else       { asm volatile("s_waitcnt vmcnt(0)" ::: "memory"); }
    __builtin_amdgcn_s_barrier();
    h8 a0[8], b0[4];
    #pragma unroll
    for (int mi = 0; mi < 8; ++mi)
      a0[mi] = *(const h8*)&lA[bt][(wr * 128 + mi * 16 + fr) * 64 + c0];
    #pragma unroll
    for (int ni = 0; ni < 4; ++ni)
      b0[ni] = *(const h8*)&lB[bt][(wc * 64 + ni * 16 + fr) * 64 + c0];
    #pragma unroll
    for (int mi = 0; mi < 8; ++mi)
      #pragma unroll
      for (int ni = 0; ni < 4; ++ni)
        acc[mi][ni] = __builtin_amdgcn_mfma_f32_16x16x32_f16(a0[mi], b0[ni], acc[mi][ni], 0, 0, 0);
    h8 a1[8], b1[4];
    #pragma unroll
    for (int mi = 0; mi < 8; ++mi)
      a1[mi] = *(const h8*)&lA[bt][(wr * 128 + mi * 16 + fr) * 64 + c1];
    #pragma unroll
    for (int ni = 0; ni < 4; ++ni)
      b1[ni] = *(const h8*)&lB[bt][(wc * 64 + ni * 16 + fr) * 64 + c1];
    asm volatile("s_waitcnt lgkmcnt(0)" ::: "memory");
    __builtin_amdgcn_sched_barrier(0);
    __builtin_amdgcn_s_barrier();
    if (t + 2 < 4) STAGE(t + 2, bt)
    __builtin_amdgcn_sched_barrier(0);
    __builtin_amdgcn_s_setprio(1);
    #pragma unroll
    for (int mi = 0; mi < 8; ++mi)
      #pragma unroll
      for (int ni = 0; ni < 4; ++ni)
        acc[mi][ni] = __builtin_amdgcn_mfma_f32_16x16x32_f16(a1[mi], b1[ni], acc[mi][ni], 0, 0, 0);
    __builtin_amdgcn_s_setprio(0);
  }
#undef STAGE

  const int er = (lane >> 4) * 4;
  #pragma unroll
  for (int mi = 0; mi < 8; ++mi) {
    #pragma unroll
    for (int ni = 0; ni < 4; ++ni) {
      #pragma unroll
      for (int r = 0; r < 4; ++r) {
        int row = wr * 128 + mi * 16 + er + r;        // q-bucket 0..255
        int col = n0 + wc * 64 + ni * 16 + fr;        // e 0..1023
        attnh[((size_t)(b * 4096 + row * 16 + j)) * 1024 + col] =
            (_Float16)acc[mi][ni][r];
      }
    }
  }
}

// ---------------- outproj: 256x256 tile, BK=64, counted-vmcnt + T2 swizzle ---
__global__ __launch_bounds__(512, 1) void gemm256_out(const _Float16* __restrict__ A,
                                                      const _Float16* __restrict__ B,
                                                      const float* __restrict__ bias,
                                                      float* __restrict__ out) {
  extern __shared__ __align__(16) _Float16 dsm[];
  _Float16 (*lA)[16384] = (_Float16 (*)[16384])dsm;             // [2][256*64]
  _Float16 (*lB)[16384] = (_Float16 (*)[16384])(dsm + 32768);
  const int tid = threadIdx.x, lane = tid & 63, w = tid >> 6;
  const int wr = w >> 2, wc = w & 3;
  int bx = blockIdx.x;
  int wid = ((bx & 7) << 6) + (bx >> 3);                        // XCD chunk of 64
  const int m0 = (wid >> 2) * 256, n0 = (wid & 3) * 256;
  const int fr = lane & 15, fk = (lane >> 4) * 8;
  const int sx = (lane & 7) << 3;
  const int c0 = fk ^ sx, c1 = (fk + 32) ^ sx;
  f32x4 acc[8][4] = {};

#define STAGE(t, buf) { \
    const int cs = ((tid & 7) ^ ((tid >> 3) & 7)) * 8; \
    const _Float16* Ag = A + (size_t)(m0 + (tid >> 3)) * 1024 + (t) * 64 + cs; \
    const _Float16* Bg = B + (size_t)(n0 + (tid >> 3)) * 1024 + (t) * 64 + cs; \
    _Float16* la0 = &lA[buf][w * 512]; \
    _Float16* lb0 = &lB[buf][w * 512]; \
    gload16(Ag,               la0); \
    gload16(Ag +  64 * 1024,  la0 + 4096); \
    gload16(Ag + 128 * 1024,  la0 + 8192); \
    gload16(Ag + 192 * 1024,  la0 + 12288); \
    gload16(Bg,               lb0); \
    gload16(Bg +  64 * 1024,  lb0 + 4096); \
    gload16(Bg + 128 * 1024,  lb0 + 8192); \
    gload16(Bg + 192 * 1024,  lb0 + 12288); \
  }

  STAGE(0, 0)
  STAGE(1, 1)

  for (int t = 0; t < 16; ++t) {
    const int bt = t & 1;
    if (t < 15) { asm volatile("s_waitcnt vmcnt(8)" ::: "memory"); }
    else        { asm volatile("s_waitcnt vmcnt(0)" ::: "memory"); }
    __builtin_amdgcn_s_barrier();
    h8 a0[8], b0[4];
    #pragma unroll
    for (int mi = 0; mi < 8; ++mi)
      a0[mi] = *(const h8*)&lA[bt][(wr * 128 + mi * 16 + fr) * 64 + c0];
    #pragma unroll
    for (int ni = 0; ni < 4; ++ni)
      b0[ni] = *(const h8*)&lB[bt][(wc * 64 + ni * 16 + fr) * 64 + c0];
    #pragma unroll
    for (int mi = 0; mi < 8; ++mi)
      #pragma unroll
      for (int ni = 0; ni < 4; ++ni)
        acc[mi][ni] = __builtin_amdgcn_mfma_f32_16x16x32_f16(a0[mi], b0[ni], acc[mi][ni], 0, 0, 0);
    h8 a1[8], b1[4];
    #pragma unroll
    for (int mi = 0; mi < 8; ++mi)
      a1[mi] = *(const h8*)&lA[bt][(wr * 128 + mi * 16 + fr) * 64 + c1];
    #pragma unroll
    for (int ni = 0; ni < 4; ++ni)
      b1[ni] = *(const h8*)&lB[bt][(wc * 64 + ni * 16 + fr) * 64 + c1];
    asm volatile("s_waitcnt lgkmcnt(0)" ::: "memory");
    __builtin_amdgcn_sched_barrier(0);
    __builtin_amdgcn_s_barrier();
    if (t + 2 < 16) STAGE(t + 2, bt)
    __builtin_amdgcn_sched_barrier(0);
    __builtin_amdgcn_s_setprio(1);
    #pragma unroll
    for (int mi = 0; mi < 8; ++mi)
      #pragma unroll
      for (int ni = 0; ni < 4; ++ni)
        acc[mi][ni] = __builtin_amdgcn_mfma_f32_16x16x32_f16(a1[mi], b1[ni], acc[mi][ni], 0, 0, 0);
    __builtin_amdgcn_s_setprio(0);
  }
#undef STAGE

  const int er = (lane >> 4) * 4;
  #pragma unroll
  for (int mi = 0; mi < 8; ++mi) {
    #pragma unroll
    for (int ni = 0; ni < 4; ++ni) {
      #pragma unroll
      for (int r = 0; r < 4; ++r) {
        int row = m0 + wr * 128 + mi * 16 + er + r;   // = b*4096 + t
        int col = n0 + wc * 64 + ni * 16 + fr;
        int bb = row >> 12, tt = row & 4095;
        out[((size_t)tt * 8 + bb) * 1024 + col] = acc[mi][ni][r] + bias[col];
      }
    }
  }
}

// -----------------------------------------------------------------------------
extern "C" void kernel_launch(void* const* d_in, const int* in_sizes, int n_in,
                              void* d_out, int out_size, void* d_ws, size_t ws_size,
                              hipStream_t stream) {
  const float* query = (const float*)d_in[0];
  const float* key   = (const float*)d_in[1];
  const float* value = (const float*)d_in[2];
  const float* wq    = (const float*)d_in[3];
  const float* bq    = (const float*)d_in[4];
  const float* wk    = (const float*)d_in[5];
  const float* bk    = (const float*)d_in[6];
  const float* wo    = (const float*)d_in[7];
  const float* bo    = (const float*)d_in[8];

  float* out      = (float*)d_out;
  float* attnw    = out + OUT_ELEMS;            // 8*256*256
  float* logalpha = out + OUT_ELEMS + AW_ELEMS; // logits (pre-noise)

  char* ws = (char*)d_ws;
  const size_t MB = 1024 * 1024;
  _Float16* wqh   = (_Float16*)(ws + 0 * MB);   // 2 MB  (wkh at +2MB, woh at +4MB)
  _Float16* woh   = (_Float16*)(ws + 4 * MB);   // 2 MB
  _Float16* qbar  = (_Float16*)(ws + 6 * MB);   // 4 MB  (2048x1024; kbar at +4MB)
  _Float16* kbar  = (_Float16*)(ws + 10 * MB);  // 4 MB
  _Float16* qbh   = (_Float16*)(ws + 14 * MB);  // 4 MB  (kbh at +4MB)
  _Float16* kbh   = (_Float16*)(ws + 18 * MB);  // 4 MB
  float*    ebuf  = (float*)(ws + 22 * MB);     // 2 MB  exp-domain entries
  _Float16* wsh   = (_Float16*)(ws + 25 * MB);  // 1 MB  attn weights f16
  _Float16* vt    = (_Float16*)(ws + 26 * MB);  // 64 MB vt[b][j][e][k]
  _Float16* attnh = (_Float16*)(ws + 90 * MB);  // 64 MB attn (B,T,E) f16
  (void)in_sizes; (void)n_in; (void)out_size; (void)ws_size;

  cb_k<<<dim3(11264), 256, 0, stream>>>(wq, wk, wo, wqh, query, key, qbar, kbar);

  gemm128<0><<<dim3(128, 1, 2), 256, 0, stream>>>(qbar, wqh, bq, bk, qbh, 1024, 1024, 1024);
  gemm128<1><<<dim3(2, 2, 8), 256, 0, stream>>>(qbh, kbh, nullptr, nullptr, logalpha, 1024, 1024, 1024);

  gumbel_k<<<dim3(2048), 256, 0, stream>>>(logalpha, ebuf);
  sinkvt_k<<<dim3(2056), 1024, 0, stream>>>(ebuf, attnw, wsh, value, vt);

  gemm256_att<<<dim3(512), 512, 131072, stream>>>(wsh, vt, attnh);
  gemm256_out<<<dim3(512), 512, 131072, stream>>>(attnh, woh, bo, out);
}

// Round 29
// 319.484 us; speedup vs baseline: 1.2597x; 1.0097x over previous
//
#include <hip/hip_runtime.h>

// SinkhornAttention on MI355X — r28 + one-load-per-thread bucket mean.
// r18-r26 plateau explained by Little's law: chained per-thread loads (reg
// variants) or DMA-queue depth (gload_lds variants) both cap in-flight bytes.
// Fix: 1 independent f32x4 load per thread (1024 thr/block, wave = 1KB
// coalesced), LDS component-split park, 64-thread reduce. 2048 loads in
// flight per CU -> HBM-bound.
// All other kernels byte-identical to r28 (322.6us, absmax 0.015625).
// T=S=4096, B=8, E=1024, BUCKET=16 -> nb=nkb=256. TAU=0.75, ITERS=8, SCALE=1/32.
// Noise (verified r7): threefry2x32 partitionable, counts (0,i), draw = o0 ^ o1.

typedef float    f32x4 __attribute__((ext_vector_type(4)));
typedef _Float16 h4    __attribute__((ext_vector_type(4)));
typedef _Float16 h8    __attribute__((ext_vector_type(8)));

#define OUT_ELEMS 33554432
#define AW_ELEMS  524288

__device__ __forceinline__ void gload16(const void* g, void* l) {
  __builtin_amdgcn_global_load_lds((__attribute__((address_space(1))) void*)g,
                                   (__attribute__((address_space(3))) void*)l,
                                   16, 0, 0);
}

// ---------------- fused: weight f32->f16 (blocks 0-767) ∥ bucket mean --------
// Bucket block = (src, bucket i, batch b, quarter): thread (j=tid>>6, s=tid&63)
// loads query[((i*16+j)*8+b)*1024 + qtr*256 + s*4] (one f32x4, independent),
// parks in lds[j][c][s]; threads <64 reduce 16 j's and write h4.
__global__ __launch_bounds__(1024) void cb_k(const float* __restrict__ wq,
                                             const float* __restrict__ wk,
                                             const float* __restrict__ wo,
                                             _Float16* __restrict__ wdst,
                                             const float* __restrict__ q,
                                             const float* __restrict__ k,
                                             _Float16* __restrict__ qbar,
                                             _Float16* __restrict__ kbar) {
  __shared__ float lds[16][4][64];                               // 16 KB
  int bid = blockIdx.x;
  int tid = threadIdx.x;
  if (bid < 768) {
    int which = bid >> 8;
    const float* src = which == 0 ? wq : (which == 1 ? wk : wo);
    size_t idx = (size_t)(bid & 255) * 1024 + tid;               // f32x4 index
    f32x4 v = ((const f32x4*)src)[idx];
    ((h4*)(wdst + (size_t)which * 1048576))[idx] = __builtin_convertvector(v, h4);
  } else {
    int g = bid - 768;                                           // 0..16383
    int srcid = g >> 13;
    int rem = g & 8191;
    int ii = rem >> 5, bb = (rem >> 2) & 7, qtr = rem & 3;
    const float* s2 = srcid ? k : q;
    _Float16* d2 = srcid ? kbar : qbar;
    int j = tid >> 6, s = tid & 63;
    f32x4 v = *(const f32x4*)(s2 + (size_t)((ii * 16 + j) * 8 + bb) * 1024
                              + qtr * 256 + s * 4);
    lds[j][0][s] = v[0];
    lds[j][1][s] = v[1];
    lds[j][2][s] = v[2];
    lds[j][3][s] = v[3];
    __syncthreads();
    if (tid < 64) {
      float a0 = 0.f, a1 = 0.f, a2 = 0.f, a3 = 0.f;
      #pragma unroll
      for (int jj = 0; jj < 16; ++jj) {
        a0 += lds[jj][0][tid];
        a1 += lds[jj][1][tid];
        a2 += lds[jj][2][tid];
        a3 += lds[jj][3][tid];
      }
      h4 hv;
      hv[0] = (_Float16)(a0 * 0.0625f);
      hv[1] = (_Float16)(a1 * 0.0625f);
      hv[2] = (_Float16)(a2 * 0.0625f);
      hv[3] = (_Float16)(a3 * 0.0625f);
      ((h4*)(d2 + (size_t)(bb * 256 + ii) * 1024 + qtr * 256))[tid] = hv;
    }
  }
}

// ---------------- JAX threefry2x32 gumbel (verified r7) ----------------------
__device__ __forceinline__ unsigned rotl32(unsigned x, int r) {
  return (x << r) | (x >> (32 - r));
}
__global__ __launch_bounds__(256) void gumbel_k(const float* __restrict__ logits,
                                                float* __restrict__ ebuf) {
  unsigned i = blockIdx.x * 256 + threadIdx.x;                    // 0..524287
  const unsigned k0 = 0u, k1 = 42u, k2 = 0u ^ 42u ^ 0x1BD11BDAu;
  unsigned x0 = 0u + k0, x1 = i + k1;                             // counts (hi,lo)=(0,i)
#define R4(a,b,c,d) \
  x0 += x1; x1 = rotl32(x1, a); x1 ^= x0; \
  x0 += x1; x1 = rotl32(x1, b); x1 ^= x0; \
  x0 += x1; x1 = rotl32(x1, c); x1 ^= x0; \
  x0 += x1; x1 = rotl32(x1, d); x1 ^= x0;
  R4(13,15,26,6)  x0 += k1; x1 += k2 + 1u;
  R4(17,29,16,24) x0 += k2; x1 += k0 + 2u;
  R4(13,15,26,6)  x0 += k0; x1 += k1 + 3u;
  R4(17,29,16,24) x0 += k1; x1 += k2 + 4u;
  R4(13,15,26,6)  x0 += k2; x1 += k0 + 5u;
#undef R4
  unsigned bits = x0 ^ x1;
  float u = __builtin_bit_cast(float, (bits >> 9) | 0x3f800000u) - 1.0f;
  float g = -logf(-logf(u + 1e-6f) + 1e-6f);
  ebuf[i] = __expf((logits[i] + g) / 0.75f);
}

// ---------------- fused: sinkhorn (blocks 0-7) ∥ V-transpose (blocks 8+) -----
__global__ __launch_bounds__(1024) void sinkvt_k(const float* __restrict__ ein,
                                                 float* __restrict__ attnw,
                                                 _Float16* __restrict__ wsh,
                                                 const float* __restrict__ v,
                                                 _Float16* __restrict__ vt) {
  __shared__ __attribute__((aligned(16))) char smem[36864];
  const int t = threadIdx.x;
  if (blockIdx.x < 8) {
    const int b = blockIdx.x;
    const int r = t >> 2, p = t & 3;       // row-sweep role
    const int k = t & 255, g = t >> 8;     // col-sweep role
    const float* Eb = ein + (size_t)b * 65536;
    const f32x4* Eb4 = (const f32x4*)Eb;
    float* ra = (float*)smem;                       // 256
    float* cb = ra + 256;                           // 256
    float (*part)[256] = (float (*)[256])(cb + 256);// 4x256
    if (t < 256) cb[t] = 1.0f;
    __syncthreads();
    const f32x4* cb4 = (const f32x4*)cb;

    for (int it = 0; it < 8; ++it) {
      float s = 0.f;
      #pragma unroll
      for (int i = 0; i < 16; ++i) {
        f32x4 e = Eb4[r * 64 + p * 16 + i];
        f32x4 c = cb4[p * 16 + i];
        f32x4 m = e * c;
        s += (m[0] + m[1]) + (m[2] + m[3]);
      }
      s += __shfl_xor(s, 1, 64);
      s += __shfl_xor(s, 2, 64);
      if (p == 0) ra[r] = 1.0f / s;
      __syncthreads();
      float s2 = 0.f;
      #pragma unroll 8
      for (int q2 = 0; q2 < 64; ++q2) {
        int row = g * 64 + q2;
        s2 += Eb[row * 256 + k] * ra[row];
      }
      part[g][k] = s2;
      __syncthreads();
      if (t < 256) {
        cb[t] = 1.0f / (part[0][t] + part[1][t] + part[2][t] + part[3][t]);
      }
      __syncthreads();
    }

    const float arow = ra[r];
    f32x4* aw = (f32x4*)(attnw + (size_t)b * 65536 + r * 256 + p * 64);
    h4* wh = (h4*)(wsh + (size_t)b * 65536 + r * 256 + p * 64);
    #pragma unroll
    for (int i = 0; i < 16; ++i) {
      f32x4 e = Eb4[r * 64 + p * 16 + i];
      f32x4 c = cb4[p * 16 + i];
      f32x4 w = e * c * arow;
      aw[i] = w;
      h4 hv;
      hv[0] = (_Float16)w[0]; hv[1] = (_Float16)w[1];
      hv[2] = (_Float16)w[2]; hv[3] = (_Float16)w[3];
      wh[i] = hv;
    }
  } else {
    const int s = t >> 8, t2 = t & 255;
    int bid = (blockIdx.x - 8) * 4 + s;              // 0..8191
    _Float16 (*tile)[72] = (_Float16 (*)[72])(smem + s * 9216);
    int kb = bid & 3, eb = (bid >> 2) & 15, j = (bid >> 6) & 15;
    int b = ((bid >> 10) + (bid & 7)) & 7;  // diagonal decode (r22)
    int k0 = kb * 64, e0 = eb * 64;
    int r = t2 >> 2, qq = t2 & 3;
    const float* src = v + ((size_t)((k0 + r) * 16 + j) * 8 + b) * 1024 + e0;
    #pragma unroll
    for (int ii = 0; ii < 4; ++ii) {
      f32x4 x = ((const f32x4*)src)[qq + ii * 4];
      *(h4*)&tile[r][(qq + ii * 4) * 4] = __builtin_convertvector(x, h4);
    }
    __syncthreads();
    _Float16* dstp = vt + (((size_t)(b * 16 + j) * 1024 + e0 + r) * 256 + k0 + qq * 16);
    h8 o0, o1;
    #pragma unroll
    for (int kk = 0; kk < 8; ++kk) o0[kk] = tile[qq * 16 + kk][r];
    #pragma unroll
    for (int kk = 0; kk < 8; ++kk) o1[kk] = tile[qq * 16 + 8 + kk][r];
    *(h8*)dstp = o0;
    *(h8*)(dstp + 8) = o1;
  }
}

// ---------------- generic 128x128 NT MFMA GEMM (m97 structure) ---------------
// MODE 0: proj (grid 128 x 1 x 2, z = q/k) -> f16 out + bias (z-strided slabs)
// MODE 1: logits  (3-D grid)               -> f32 /32 to log_alpha
template <int MODE>
__global__ __launch_bounds__(256) void gemm128(const _Float16* __restrict__ A,
                                               const _Float16* __restrict__ B,
                                               const float* __restrict__ bias,
                                               const float* __restrict__ bias2,
                                               void* __restrict__ out0,
                                               int K, int lda, int ldb) {
  const int tid = threadIdx.x, lane = tid & 63, w = tid >> 6;
  int bx = blockIdx.x, by = blockIdx.y, bz = blockIdx.z;
  if constexpr (MODE == 0) {
    int wid = ((bx & 7) << 4) + (bx >> 3);
    by = wid & 7; bx = wid >> 3;
  }
  const int m0 = bx * 128, n0 = by * 128;
  const _Float16* Ab = A;
  const _Float16* Bb = B;
  const float* bs = bias;
  if constexpr (MODE == 0) {
    Ab += (size_t)bz * 2097152;        // qbar -> kbar
    Bb += (size_t)bz * 1048576;        // wqh  -> wkh
    if (bz) bs = bias2;                // bq   -> bk
  }
  if constexpr (MODE == 1) { Ab += (size_t)bz * 262144; Bb += (size_t)bz * 262144; }
  __shared__ _Float16 lA[128 * 32];
  __shared__ _Float16 lB[128 * 32];
  f32x4 acc[4][4] = {};
  const int wm = (w >> 1) * 64, wn = (w & 1) * 64;
  const int fr = lane & 15, fk = (lane >> 4) * 8;
  const int q0 = tid, q1 = tid + 256;

  for (int kt = 0; kt < K; kt += 32) {
    __syncthreads();
    gload16(Ab + (size_t)(m0 + (q0 >> 2)) * lda + kt + (q0 & 3) * 8, &lA[(w * 64) * 8]);
    gload16(Ab + (size_t)(m0 + (q1 >> 2)) * lda + kt + (q1 & 3) * 8, &lA[(256 + w * 64) * 8]);
    gload16(Bb + (size_t)(n0 + (q0 >> 2)) * ldb + kt + (q0 & 3) * 8, &lB[(w * 64) * 8]);
    gload16(Bb + (size_t)(n0 + (q1 >> 2)) * ldb + kt + (q1 & 3) * 8, &lB[(256 + w * 64) * 8]);
    __syncthreads();
    h8 af[4], bf[4];
    #pragma unroll
    for (int i = 0; i < 4; ++i) {
      af[i] = *(const h8*)&lA[(wm + i * 16 + fr) * 32 + fk];
      bf[i] = *(const h8*)&lB[(wn + i * 16 + fr) * 32 + fk];
    }
    #pragma unroll
    for (int mi = 0; mi < 4; ++mi)
      #pragma unroll
      for (int ni = 0; ni < 4; ++ni)
        acc[mi][ni] = __builtin_amdgcn_mfma_f32_16x16x32_f16(af[mi], bf[ni], acc[mi][ni], 0, 0, 0);
  }

  const int er = (lane >> 4) * 4;
  #pragma unroll
  for (int mi = 0; mi < 4; ++mi) {
    #pragma unroll
    for (int ni = 0; ni < 4; ++ni) {
      #pragma unroll
      for (int r = 0; r < 4; ++r) {
        int row = m0 + wm + mi * 16 + er + r;
        int col = n0 + wn + ni * 16 + fr;
        float val = acc[mi][ni][r];
        if constexpr (MODE == 0) {
          ((_Float16*)out0)[(size_t)bz * 2097152 + (size_t)row * 1024 + col] =
              (_Float16)(val + bs[col]);
        } else {
          ((float*)out0)[(size_t)bz * 65536 + row * 256 + col] = val * 0.03125f;
        }
      }
    }
  }
}

// ---------------- attn: 256-row tile, BK=64, counted-vmcnt + T2 swizzle ------
__global__ __launch_bounds__(512, 1) void gemm256_att(const _Float16* __restrict__ W,
                                                      const _Float16* __restrict__ V,
                                                      _Float16* __restrict__ attnh) {
  extern __shared__ __align__(16) _Float16 dsm[];
  _Float16 (*lA)[16384] = (_Float16 (*)[16384])dsm;             // [2][256*64]
  _Float16 (*lB)[16384] = (_Float16 (*)[16384])(dsm + 32768);
  const int tid = threadIdx.x, lane = tid & 63, w = tid >> 6;
  const int wr = w >> 2, wc = w & 3;
  int bx = blockIdx.x;
  int wid = ((bx & 7) << 6) + (bx >> 3);                        // XCD chunk of 64
  const int bj = wid >> 2, nt = wid & 3;
  const int b = bj >> 4, j = bj & 15;
  const int n0 = nt * 256;
  const _Float16* A = W + (size_t)b * 65536;                    // [256][256]
  const _Float16* B = V + (size_t)bj * 262144;                  // [1024][256]
  const int fr = lane & 15, fk = (lane >> 4) * 8;
  const int sx = (lane & 7) << 3;
  const int c0 = fk ^ sx, c1 = (fk + 32) ^ sx;
  f32x4 acc[8][4] = {};

#define STAGE(t, buf) { \
    const int cs = ((tid & 7) ^ ((tid >> 3) & 7)) * 8; \
    const _Float16* Ag = A + (size_t)(tid >> 3) * 256 + (t) * 64 + cs; \
    const _Float16* Bg = B + (size_t)(n0 + (tid >> 3)) * 256 + (t) * 64 + cs; \
    _Float16* la0 = &lA[buf][w * 512]; \
    _Float16* lb0 = &lB[buf][w * 512]; \
    gload16(Ag,              la0); \
    gload16(Ag +  64 * 256,  la0 + 4096); \
    gload16(Ag + 128 * 256,  la0 + 8192); \
    gload16(Ag + 192 * 256,  la0 + 12288); \
    gload16(Bg,              lb0); \
    gload16(Bg +  64 * 256,  lb0 + 4096); \
    gload16(Bg + 128 * 256,  lb0 + 8192); \
    gload16(Bg + 192 * 256,  lb0 + 12288); \
  }

  STAGE(0, 0)
  STAGE(1, 1)

  for (int t = 0; t < 4; ++t) {
    const int bt = t & 1;
    if (t < 3) { asm volatile("s_waitcnt vmcnt(8)" ::: "memory"); }
    else       { asm volatile("s_waitcnt vmcnt(0)" ::: "memory"); }
    __builtin_amdgcn_s_barrier();
    h8 a0[8], b0[4];
    #pragma unroll
    for (int mi = 0; mi < 8; ++mi)
      a0[mi] = *(const h8*)&lA[bt][(wr * 128 + mi * 16 + fr) * 64 + c0];
    #pragma unroll
    for (int ni = 0; ni < 4; ++ni)
      b0[ni] = *(const h8*)&lB[bt][(wc * 64 + ni * 16 + fr) * 64 + c0];
    #pragma unroll
    for (int mi = 0; mi < 8; ++mi)
      #pragma unroll
      for (int ni = 0; ni < 4; ++ni)
        acc[mi][ni] = __builtin_amdgcn_mfma_f32_16x16x32_f16(a0[mi], b0[ni], acc[mi][ni], 0, 0, 0);
    h8 a1[8], b1[4];
    #pragma unroll
    for (int mi = 0; mi < 8; ++mi)
      a1[mi] = *(const h8*)&lA[bt][(wr * 128 + mi * 16 + fr) * 64 + c1];
    #pragma unroll
    for (int ni = 0; ni < 4; ++ni)
      b1[ni] = *(const h8*)&lB[bt][(wc * 64 + ni * 16 + fr) * 64 + c1];
    asm volatile("s_waitcnt lgkmcnt(0)" ::: "memory");
    __builtin_amdgcn_sched_barrier(0);
    __builtin_amdgcn_s_barrier();
    if (t + 2 < 4) STAGE(t + 2, bt)
    __builtin_amdgcn_sched_barrier(0);
    __builtin_amdgcn_s_setprio(1);
    #pragma unroll
    for (int mi = 0; mi < 8; ++mi)
      #pragma unroll
      for (int ni = 0; ni < 4; ++ni)
        acc[mi][ni] = __builtin_amdgcn_mfma_f32_16x16x32_f16(a1[mi], b1[ni], acc[mi][ni], 0, 0, 0);
    __builtin_amdgcn_s_setprio(0);
  }
#undef STAGE

  const int er = (lane >> 4) * 4;
  #pragma unroll
  for (int mi = 0; mi < 8; ++mi) {
    #pragma unroll
    for (int ni = 0; ni < 4; ++ni) {
      #pragma unroll
      for (int r = 0; r < 4; ++r) {
        int row = wr * 128 + mi * 16 + er + r;        // q-bucket 0..255
        int col = n0 + wc * 64 + ni * 16 + fr;        // e 0..1023
        attnh[((size_t)(b * 4096 + row * 16 + j)) * 1024 + col] =
            (_Float16)acc[mi][ni][r];
      }
    }
  }
}

// ---------------- outproj: 256x256 tile, BK=64, counted-vmcnt + T2 swizzle ---
__global__ __launch_bounds__(512, 1) void gemm256_out(const _Float16* __restrict__ A,
                                                      const _Float16* __restrict__ B,
                                                      const float* __restrict__ bias,
                                                      float* __restrict__ out) {
  extern __shared__ __align__(16) _Float16 dsm[];
  _Float16 (*lA)[16384] = (_Float16 (*)[16384])dsm;             // [2][256*64]
  _Float16 (*lB)[16384] = (_Float16 (*)[16384])(dsm + 32768);
  const int tid = threadIdx.x, lane = tid & 63, w = tid >> 6;
  const int wr = w >> 2, wc = w & 3;
  int bx = blockIdx.x;
  int wid = ((bx & 7) << 6) + (bx >> 3);                        // XCD chunk of 64
  const int m0 = (wid >> 2) * 256, n0 = (wid & 3) * 256;
  const int fr = lane & 15, fk = (lane >> 4) * 8;
  const int sx = (lane & 7) << 3;
  const int c0 = fk ^ sx, c1 = (fk + 32) ^ sx;
  f32x4 acc[8][4] = {};

#define STAGE(t, buf) { \
    const int cs = ((tid & 7) ^ ((tid >> 3) & 7)) * 8; \
    const _Float16* Ag = A + (size_t)(m0 + (tid >> 3)) * 1024 + (t) * 64 + cs; \
    const _Float16* Bg = B + (size_t)(n0 + (tid >> 3)) * 1024 + (t) * 64 + cs; \
    _Float16* la0 = &lA[buf][w * 512]; \
    _Float16* lb0 = &lB[buf][w * 512]; \
    gload16(Ag,               la0); \
    gload16(Ag +  64 * 1024,  la0 + 4096); \
    gload16(Ag + 128 * 1024,  la0 + 8192); \
    gload16(Ag + 192 * 1024,  la0 + 12288); \
    gload16(Bg,               lb0); \
    gload16(Bg +  64 * 1024,  lb0 + 4096); \
    gload16(Bg + 128 * 1024,  lb0 + 8192); \
    gload16(Bg + 192 * 1024,  lb0 + 12288); \
  }

  STAGE(0, 0)
  STAGE(1, 1)

  for (int t = 0; t < 16; ++t) {
    const int bt = t & 1;
    if (t < 15) { asm volatile("s_waitcnt vmcnt(8)" ::: "memory"); }
    else        { asm volatile("s_waitcnt vmcnt(0)" ::: "memory"); }
    __builtin_amdgcn_s_barrier();
    h8 a0[8], b0[4];
    #pragma unroll
    for (int mi = 0; mi < 8; ++mi)
      a0[mi] = *(const h8*)&lA[bt][(wr * 128 + mi * 16 + fr) * 64 + c0];
    #pragma unroll
    for (int ni = 0; ni < 4; ++ni)
      b0[ni] = *(const h8*)&lB[bt][(wc * 64 + ni * 16 + fr) * 64 + c0];
    #pragma unroll
    for (int mi = 0; mi < 8; ++mi)
      #pragma unroll
      for (int ni = 0; ni < 4; ++ni)
        acc[mi][ni] = __builtin_amdgcn_mfma_f32_16x16x32_f16(a0[mi], b0[ni], acc[mi][ni], 0, 0, 0);
    h8 a1[8], b1[4];
    #pragma unroll
    for (int mi = 0; mi < 8; ++mi)
      a1[mi] = *(const h8*)&lA[bt][(wr * 128 + mi * 16 + fr) * 64 + c1];
    #pragma unroll
    for (int ni = 0; ni < 4; ++ni)
      b1[ni] = *(const h8*)&lB[bt][(wc * 64 + ni * 16 + fr) * 64 + c1];
    asm volatile("s_waitcnt lgkmcnt(0)" ::: "memory");
    __builtin_amdgcn_sched_barrier(0);
    __builtin_amdgcn_s_barrier();
    if (t + 2 < 16) STAGE(t + 2, bt)
    __builtin_amdgcn_sched_barrier(0);
    __builtin_amdgcn_s_setprio(1);
    #pragma unroll
    for (int mi = 0; mi < 8; ++mi)
      #pragma unroll
      for (int ni = 0; ni < 4; ++ni)
        acc[mi][ni] = __builtin_amdgcn_mfma_f32_16x16x32_f16(a1[mi], b1[ni], acc[mi][ni], 0, 0, 0);
    __builtin_amdgcn_s_setprio(0);
  }
#undef STAGE

  const int er = (lane >> 4) * 4;
  #pragma unroll
  for (int mi = 0; mi < 8; ++mi) {
    #pragma unroll
    for (int ni = 0; ni < 4; ++ni) {
      #pragma unroll
      for (int r = 0; r < 4; ++r) {
        int row = m0 + wr * 128 + mi * 16 + er + r;   // = b*4096 + t
        int col = n0 + wc * 64 + ni * 16 + fr;
        int bb = row >> 12, tt = row & 4095;
        out[((size_t)tt * 8 + bb) * 1024 + col] = acc[mi][ni][r] + bias[col];
      }
    }
  }
}

// -----------------------------------------------------------------------------
extern "C" void kernel_launch(void* const* d_in, const int* in_sizes, int n_in,
                              void* d_out, int out_size, void* d_ws, size_t ws_size,
                              hipStream_t stream) {
  const float* query = (const float*)d_in[0];
  const float* key   = (const float*)d_in[1];
  const float* value = (const float*)d_in[2];
  const float* wq    = (const float*)d_in[3];
  const float* bq    = (const float*)d_in[4];
  const float* wk    = (const float*)d_in[5];
  const float* bk    = (const float*)d_in[6];
  const float* wo    = (const float*)d_in[7];
  const float* bo    = (const float*)d_in[8];

  float* out      = (float*)d_out;
  float* attnw    = out + OUT_ELEMS;            // 8*256*256
  float* logalpha = out + OUT_ELEMS + AW_ELEMS; // logits (pre-noise)

  char* ws = (char*)d_ws;
  const size_t MB = 1024 * 1024;
  _Float16* wqh   = (_Float16*)(ws + 0 * MB);   // 2 MB  (wkh at +2MB, woh at +4MB)
  _Float16* woh   = (_Float16*)(ws + 4 * MB);   // 2 MB
  _Float16* qbar  = (_Float16*)(ws + 6 * MB);   // 4 MB  (2048x1024; kbar at +4MB)
  _Float16* kbar  = (_Float16*)(ws + 10 * MB);  // 4 MB
  _Float16* qbh   = (_Float16*)(ws + 14 * MB);  // 4 MB  (kbh at +4MB)
  _Float16* kbh   = (_Float16*)(ws + 18 * MB);  // 4 MB
  float*    ebuf  = (float*)(ws + 22 * MB);     // 2 MB  exp-domain entries
  _Float16* wsh   = (_Float16*)(ws + 25 * MB);  // 1 MB  attn weights f16
  _Float16* vt    = (_Float16*)(ws + 26 * MB);  // 64 MB vt[b][j][e][k]
  _Float16* attnh = (_Float16*)(ws + 90 * MB);  // 64 MB attn (B,T,E) f16
  (void)in_sizes; (void)n_in; (void)out_size; (void)ws_size;

  cb_k<<<dim3(17152), 1024, 0, stream>>>(wq, wk, wo, wqh, query, key, qbar, kbar);

  gemm128<0><<<dim3(128, 1, 2), 256, 0, stream>>>(qbar, wqh, bq, bk, qbh, 1024, 1024, 1024);
  gemm128<1><<<dim3(2, 2, 8), 256, 0, stream>>>(qbh, kbh, nullptr, nullptr, logalpha, 1024, 1024, 1024);

  gumbel_k<<<dim3(2048), 256, 0, stream>>>(logalpha, ebuf);
  sinkvt_k<<<dim3(2056), 1024, 0, stream>>>(ebuf, attnw, wsh, value, vt);

  gemm256_att<<<dim3(512), 512, 131072, stream>>>(wsh, vt, attnh);
  gemm256_out<<<dim3(512), 512, 131072, stream>>>(attnh, woh, bo, out);
}